// Round 1
// 408.568 us; speedup vs baseline: 1.0489x; 1.0489x over previous
//
#include <hip/hip_runtime.h>

// GaussianAgg: z_map construction + S=16 perturbed argmaxes -> mean one-hot.
// Memory-bound: noise [16,131072,33] f32 = 277 MB dominates.
// v2: direct HBM->LDS staging via global_load_lds (no VGPR round-trip),
//     double-buffered noise tiles, ONE barrier per sample with next-sample
//     loads in flight during current-sample compute (2-phase pipeline).

#define NPIX   (8 * 128 * 128)   // 131072
#define KCH    32
#define CCH    33                // K + background
#define SAMP   16
#define TPB    256
#define TILE   (TPB * CCH)       // floats per sample tile = 8448 (33.8 KB)

// direct global->LDS DMA, 16 bytes per lane; lane mapping is linear
// (wave-uniform LDS base + lane*16), which matches this copy exactly.
#define GLL16(gp, lp)                                                     \
    __builtin_amdgcn_global_load_lds(                                     \
        (const __attribute__((address_space(1))) void*)(gp),              \
        (__attribute__((address_space(3))) void*)(lp), 16, 0, 0)

__device__ __forceinline__ void stage_tile(const float* __restrict__ gsrc,
                                           float* ldst, int tid)
{
    // 2112 float4 copies: 8 full rounds of 256 threads + 64-wide tail (wave 0)
    #pragma unroll
    for (int j = 0; j < (TILE / 4) / TPB; ++j) {
        const int i = tid + j * TPB;
        GLL16(gsrc + 4 * i, ldst + 4 * i);
    }
    if (tid < (TILE / 4) - ((TILE / 4) / TPB) * TPB) {   // 64 leftover float4
        const int i = tid + ((TILE / 4) / TPB) * TPB;
        GLL16(gsrc + 4 * i, ldst + 4 * i);
    }
}

__global__ __launch_bounds__(TPB)
void gauss_agg_kernel(const float* __restrict__ zbuf,
                      const float* __restrict__ zfar_p,
                      const float* __restrict__ znear_p,
                      const float* __restrict__ prob,
                      const float* __restrict__ mask,
                      const float* __restrict__ noise,
                      float* __restrict__ out)
{
#pragma clang fp contract(off)
    __shared__ float lds[2 * TILE];   // double-buffered noise tile (67.6 KB)
    const int tid = threadIdx.x;
    const int p0  = blockIdx.x * TPB;   // first pixel of this block
    const size_t p = (size_t)p0 + tid;  // this thread's pixel

    // ---- issue sample-0 noise staging immediately; prologue hides its latency
    stage_tile(noise + ((size_t)0 * NPIX + p0) * CCH, lds, tid);

    const float zfar  = zfar_p[0];
    const float znear = znear_p[0];
    const float denom = zfar - znear;

    // ---- load this pixel's zbuf/prob/mask rows (32 contiguous floats)
    float zb[KCH], pm[KCH], mk[KCH];
    {
        const float4* zb4 = reinterpret_cast<const float4*>(zbuf + p * KCH);
        const float4* pm4 = reinterpret_cast<const float4*>(prob + p * KCH);
        const float4* mk4 = reinterpret_cast<const float4*>(mask + p * KCH);
        #pragma unroll
        for (int i = 0; i < KCH / 4; ++i) {
            float4 a = zb4[i], b = pm4[i], c = mk4[i];
            zb[4*i+0] = a.x; zb[4*i+1] = a.y; zb[4*i+2] = a.z; zb[4*i+3] = a.w;
            pm[4*i+0] = b.x; pm[4*i+1] = b.y; pm[4*i+2] = b.z; pm[4*i+3] = b.w;
            mk[4*i+0] = c.x; mk[4*i+1] = c.y; mk[4*i+2] = c.z; mk[4*i+3] = c.w;
        }
    }

    // ---- z_inv, z_inv_max (EPS folded into max; max is exact, order-safe)
    float z_inv[KCH];
    float zmax = 1e-10f;
    #pragma unroll
    for (int k = 0; k < KCH; ++k) {
        float zi = ((zfar - zb[k]) / denom) * mk[k];
        z_inv[k] = zi;
        zmax = fmaxf(zmax, zi);
    }

    // ---- z_map[33], rounding order matching ref: ((g*log) + z_inv) - zmax
    float z_map[CCH];
    #pragma unroll
    for (int k = 0; k < KCH; ++k) {
        float lg = logf(1e-12f + pm[k]);
        z_map[k] = ((0.04f * lg) + z_inv[k]) - zmax;
    }
    z_map[KCH] = 1e-10f - zmax;

    int acc[CCH];
    #pragma unroll
    for (int c = 0; c < CCH; ++c) acc[c] = 0;

    __syncthreads();   // drains stage(0) (vmcnt(0) implied by barrier)

    // ---- pipelined sample loop: stage(s+1) in flight during compute(s),
    //      single barrier per sample drains it for the next iteration.
    for (int s = 0; s < SAMP; ++s) {
        if (s + 1 < SAMP)
            stage_tile(noise + ((size_t)(s + 1) * NPIX + p0) * CCH,
                       lds + ((s + 1) & 1) * TILE, tid);

        const float* cur = lds + (s & 1) * TILE;
        const int base = tid * CCH;
        float best = z_map[0] + (0.04f * cur[base + 0]);
        int bi = 0;
        #pragma unroll
        for (int c = 1; c < CCH; ++c) {
            float v = z_map[c] + (0.04f * cur[base + c]);
            if (v > best) { best = v; bi = c; }
        }
        #pragma unroll
        for (int c = 0; c < CCH; ++c) acc[c] += (bi == c) ? 1 : 0;

        __syncthreads();   // stage(s+1) complete; cur free for s+2's stage
    }

    // ---- write counts/16 through LDS (buffer 0) for coalesced float4 stores
    {
        const int base = tid * CCH;
        #pragma unroll
        for (int c = 0; c < CCH; ++c)
            lds[base + c] = (float)acc[c] * 0.0625f;  // exact
    }
    __syncthreads();
    {
        const float4* l4 = reinterpret_cast<const float4*>(lds);
        float4* o4 = reinterpret_cast<float4*>(out + (size_t)p0 * CCH);
        for (int i = tid; i < TILE / 4; i += TPB) o4[i] = l4[i];
    }
}

extern "C" void kernel_launch(void* const* d_in, const int* in_sizes, int n_in,
                              void* d_out, int out_size, void* d_ws, size_t ws_size,
                              hipStream_t stream)
{
    const float* zbuf  = (const float*)d_in[0];
    const float* zfar  = (const float*)d_in[1];
    const float* znear = (const float*)d_in[2];
    const float* prob  = (const float*)d_in[3];
    const float* mask  = (const float*)d_in[4];
    const float* noise = (const float*)d_in[5];
    float* out = (float*)d_out;

    dim3 grid(NPIX / TPB), block(TPB);
    gauss_agg_kernel<<<grid, block, 0, stream>>>(zbuf, zfar, znear, prob, mask,
                                                 noise, out);
}

// Round 2
// 408.209 us; speedup vs baseline: 1.0499x; 1.0009x over previous
//
#include <hip/hip_runtime.h>

// GaussianAgg: z_map construction + S=16 perturbed argmaxes -> mean one-hot.
// Memory-bound: noise [16,131072,33] f32 = 277 MB dominates.
// v3: per-WAVE self-staging via global_load_lds + counted vmcnt(9) waits.
//     No barriers in the sample loop (T3/T4): each wave owns its private
//     2112-float LDS slice, issues tile s+1's 9 DMA ops, waits vmcnt(9)
//     (tile s landed, tile s+1 in flight), computes. HBM never drains.

#define NPIX   (8 * 128 * 128)   // 131072
#define KCH    32
#define CCH    33                // K + background
#define SAMP   16
#define TPB    256
#define TILE   (TPB * CCH)       // floats per sample tile = 8448 (33.8 KB)
#define WFLOATS (64 * CCH)       // 2112 floats per wave slice (8448 B)

// direct global->LDS DMA, 16 bytes per lane; lane mapping is linear
// (wave-uniform LDS base + lane*16), which matches this copy exactly.
#define GLL16(gp, lp)                                                     \
    __builtin_amdgcn_global_load_lds(                                     \
        (const __attribute__((address_space(1))) void*)(gp),              \
        (__attribute__((address_space(3))) void*)(lp), 16, 0, 0)

// Stage one wave's private 2112-float slice: 8 full float4 rounds (512
// float4) + 16-lane tail (16 float4) = exactly 9 VMEM instructions/wave.
__device__ __forceinline__ void stage_wave(const float* __restrict__ gsrc,
                                           float* ldst, int lane)
{
    #pragma unroll
    for (int j = 0; j < 8; ++j) {
        const int f = j * 64 + lane;        // float4 index within slice
        GLL16(gsrc + 4 * f, ldst + 4 * f);
    }
    if (lane < 16) {                        // exec-masked, still 1 VMEM op
        const int f = 512 + lane;
        GLL16(gsrc + 4 * f, ldst + 4 * f);
    }
}

__device__ __forceinline__ void argmax_sample(const float* __restrict__ cur,
                                              const float* __restrict__ z_map,
                                              int* __restrict__ acc, int base)
{
    float best = z_map[0] + (0.04f * cur[base + 0]);
    int bi = 0;
    #pragma unroll
    for (int c = 1; c < CCH; ++c) {
        float v = z_map[c] + (0.04f * cur[base + c]);
        if (v > best) { best = v; bi = c; }
    }
    #pragma unroll
    for (int c = 0; c < CCH; ++c) acc[c] += (bi == c) ? 1 : 0;
}

__global__ __launch_bounds__(TPB)
void gauss_agg_kernel(const float* __restrict__ zbuf,
                      const float* __restrict__ zfar_p,
                      const float* __restrict__ znear_p,
                      const float* __restrict__ prob,
                      const float* __restrict__ mask,
                      const float* __restrict__ noise,
                      float* __restrict__ out)
{
#pragma clang fp contract(off)
    __shared__ float lds[2 * TILE];   // double-buffered noise tile (67.6 KB)
    const int tid  = threadIdx.x;
    const int lane = tid & 63;
    const int wsl  = (tid >> 6) * WFLOATS;   // this wave's float offset in tile
    const int p0   = blockIdx.x * TPB;       // first pixel of this block
    const size_t p = (size_t)p0 + tid;       // this thread's pixel

    // ---- issue sample-0 staging immediately; prologue hides its latency
    stage_wave(noise + ((size_t)0 * NPIX + p0) * CCH + wsl, lds + wsl, lane);

    const float zfar  = zfar_p[0];
    const float znear = znear_p[0];
    const float denom = zfar - znear;

    // ---- load this pixel's zbuf/prob/mask rows (32 contiguous floats)
    float zb[KCH], pm[KCH], mk[KCH];
    {
        const float4* zb4 = reinterpret_cast<const float4*>(zbuf + p * KCH);
        const float4* pm4 = reinterpret_cast<const float4*>(prob + p * KCH);
        const float4* mk4 = reinterpret_cast<const float4*>(mask + p * KCH);
        #pragma unroll
        for (int i = 0; i < KCH / 4; ++i) {
            float4 a = zb4[i], b = pm4[i], c = mk4[i];
            zb[4*i+0] = a.x; zb[4*i+1] = a.y; zb[4*i+2] = a.z; zb[4*i+3] = a.w;
            pm[4*i+0] = b.x; pm[4*i+1] = b.y; pm[4*i+2] = b.z; pm[4*i+3] = b.w;
            mk[4*i+0] = c.x; mk[4*i+1] = c.y; mk[4*i+2] = c.z; mk[4*i+3] = c.w;
        }
    }

    // ---- z_inv, z_inv_max (EPS folded into max; max is exact, order-safe)
    float z_inv[KCH];
    float zmax = 1e-10f;
    #pragma unroll
    for (int k = 0; k < KCH; ++k) {
        float zi = ((zfar - zb[k]) / denom) * mk[k];
        z_inv[k] = zi;
        zmax = fmaxf(zmax, zi);
    }

    // ---- z_map[33], rounding order matching ref: ((g*log) + z_inv) - zmax
    float z_map[CCH];
    #pragma unroll
    for (int k = 0; k < KCH; ++k) {
        float lg = logf(1e-12f + pm[k]);
        z_map[k] = ((0.04f * lg) + z_inv[k]) - zmax;
    }
    z_map[KCH] = 1e-10f - zmax;

    int acc[CCH];
    #pragma unroll
    for (int c = 0; c < CCH; ++c) acc[c] = 0;

    const int base = tid * CCH - wsl;   // offset within wave slice... 
    // NOTE: cur below points at the wave slice, so index = tid*CCH - wsl = lane*CCH
    // (kept explicit for clarity)

    // ---- barrier-free pipelined sample loop (per-wave self-paced).
    //      Iter s: issue 9 DMA for tile s+1, wait vmcnt(9) => tile s landed
    //      (tile s+1 still in flight), compute tile s. HBM never drains.
    for (int s = 0; s < SAMP - 1; ++s) {
        stage_wave(noise + ((size_t)(s + 1) * NPIX + p0) * CCH + wsl,
                   lds + ((s + 1) & 1) * TILE + wsl, lane);
        asm volatile("s_waitcnt vmcnt(9)" ::: "memory");
        const float* cur = lds + (s & 1) * TILE + wsl;
        argmax_sample(cur, z_map, acc, base);
    }
    // peeled last sample: nothing left to issue, drain our own 9
    asm volatile("s_waitcnt vmcnt(0)" ::: "memory");
    {
        const float* cur = lds + ((SAMP - 1) & 1) * TILE + wsl;
        argmax_sample(cur, z_map, acc, base);
    }

    // ---- write counts/16 through LDS (each thread writes only its own
    //      slice floats -> no cross-wave hazard before the barrier)
    {
        const int b = tid * CCH;
        #pragma unroll
        for (int c = 0; c < CCH; ++c)
            lds[b + c] = (float)acc[c] * 0.0625f;  // exact
    }
    __syncthreads();   // single barrier: publish for cross-wave coalesced store
    {
        const float4* l4 = reinterpret_cast<const float4*>(lds);
        float4* o4 = reinterpret_cast<float4*>(out + (size_t)p0 * CCH);
        for (int i = tid; i < TILE / 4; i += TPB) o4[i] = l4[i];
    }
}

extern "C" void kernel_launch(void* const* d_in, const int* in_sizes, int n_in,
                              void* d_out, int out_size, void* d_ws, size_t ws_size,
                              hipStream_t stream)
{
    const float* zbuf  = (const float*)d_in[0];
    const float* zfar  = (const float*)d_in[1];
    const float* znear = (const float*)d_in[2];
    const float* prob  = (const float*)d_in[3];
    const float* mask  = (const float*)d_in[4];
    const float* noise = (const float*)d_in[5];
    float* out = (float*)d_out;

    dim3 grid(NPIX / TPB), block(TPB);
    gauss_agg_kernel<<<grid, block, 0, stream>>>(zbuf, zfar, znear, prob, mask,
                                                 noise, out);
}